// Round 9
// baseline (238.553 us; speedup 1.0000x reference)
//
#include <hip/hip_runtime.h>
#include <hip/hip_bf16.h>
#include <stdint.h>

#define N_NODES 8192
#define F_DIM 256
#define K_SEL 4096

typedef unsigned char u8;
typedef __attribute__((ext_vector_type(4))) int i32x4;
typedef __attribute__((ext_vector_type(8))) int i32x8;
typedef __attribute__((ext_vector_type(16))) float f32x16;

// 1. Xk[i] = sum_f X[i,f]*kernel[f]   (fp64 accumulate)
__global__ void xk_kernel(const float* __restrict__ X, const float* __restrict__ kern,
                          float* __restrict__ Xk) {
  __shared__ double red[256];
  int row = blockIdx.x, t = threadIdx.x;
  double p = (double)X[(size_t)row * F_DIM + t] * (double)kern[t];
  red[t] = p; __syncthreads();
  for (int off = 128; off > 0; off >>= 1) {
    if (t < off) red[t] += red[t + off];
    __syncthreads();
  }
  if (t == 0) Xk[row] = (float)red[0];
}

// 2. fused prep: ONE pass over A emits Af8 (row-major fp8), At8 (transposed
//    fp8), and per-chunk fp64 gemv partials ypart[chunk][row] (deterministic).
#define PR 128
#define PC 256
__global__ __launch_bounds__(256) void prep8(const float* __restrict__ A,
                                             const float* __restrict__ Xk,
                                             u8* __restrict__ Af8,
                                             u8* __restrict__ At8,
                                             double* __restrict__ ypart) {
  __shared__ u8 tile[PR][PC + 4];
  __shared__ float sXk[PC];
  int t = threadIdx.x, w = t >> 6, l = t & 63;
  int c0 = blockIdx.x * PC, r0 = blockIdx.y * PR;
  if (t < PC / 4) *(float4*)&sXk[t * 4] = *(const float4*)&Xk[c0 + t * 4];
  __syncthreads();
  #pragma unroll
  for (int p = 0; p < 8; ++p) {
    int r = p * 16 + (t >> 4);
    const float4* src = (const float4*)(A + (size_t)(r0 + r) * N_NODES + c0);
    // explicit ILP: issue all 4 loads before the dependent encode/dot chain
    float4 v[4];
    #pragma unroll
    for (int j = 0; j < 4; ++j) v[j] = src[(t & 15) + j * 16];
    double d = 0.0;
    #pragma unroll
    for (int j = 0; j < 4; ++j) {
      int c4 = (t & 15) + j * 16;
      float4 x = *(const float4*)&sXk[c4 * 4];
      d += (double)v[j].x * x.x + (double)v[j].y * x.y +
           (double)v[j].z * x.z + (double)v[j].w * x.w;
      int pk = __builtin_amdgcn_cvt_pk_fp8_f32(v[j].x, v[j].y, 0, false);
      pk = __builtin_amdgcn_cvt_pk_fp8_f32(v[j].z, v[j].w, pk, true);
      *(int*)&tile[r][c4 * 4] = pk;
    }
    d += __shfl_xor(d, 1); d += __shfl_xor(d, 2);
    d += __shfl_xor(d, 4); d += __shfl_xor(d, 8);
    if ((t & 15) == 0) ypart[(size_t)blockIdx.x * N_NODES + r0 + r] = d;
  }
  __syncthreads();
  // Af8 rows: 64 lanes x 4B = 256B coalesced per row
  for (int j = w; j < PR; j += 4)
    *(unsigned int*)(Af8 + (size_t)(r0 + j) * N_NODES + c0 + l * 4) =
        *(const unsigned int*)&tile[j][l * 4];
  // At8 cols: lane l packs rows {2l,2l+1} -> 128B contiguous per col
  for (int j = w; j < PC; j += 4) {
    unsigned short v = (unsigned short)(tile[2 * l][j] | (tile[2 * l + 1][j] << 8));
    *(unsigned short*)(At8 + (size_t)(c0 + j) * N_NODES + r0 + 2 * l) = v;
  }
}

// 3. y[i] = sum over 32 col-chunk partials (fp64, fixed order -> deterministic)
__global__ void yreduce(const double* __restrict__ ypart, float* __restrict__ y) {
  int i = blockIdx.x * 256 + threadIdx.x;
  double s = 0.0;
  #pragma unroll
  for (int b = 0; b < 32; ++b) s += ypart[(size_t)b * N_NODES + i];
  y[i] = (float)s;
}

// 4. partial ranks over j-chunks of 1024; 256 blocks -> full-chip
__global__ void rank2d(const float* __restrict__ y, int* __restrict__ partial) {
  __shared__ float sc[1024];
  int i = blockIdx.x * 256 + threadIdx.x;
  float si = y[i];
  int j0 = blockIdx.y * 1024;
  for (int c = threadIdx.x; c < 1024; c += 256) sc[c] = y[j0 + c];
  __syncthreads();
  int cnt = 0;
  #pragma unroll 8
  for (int jj = 0; jj < 1024; ++jj) {
    float sj = sc[jj];
    int j = j0 + jj;
    cnt += (sj > si) || (sj == si && j < i);
  }
  partial[blockIdx.y * N_NODES + i] = cnt;
}

// 5. sum partials; ordered compaction -> idx[0..K-1] ascending
__global__ void scan_kernel(const int* __restrict__ partial, int* __restrict__ idx) {
  __shared__ int ps[1024];
  int t = threadIdx.x;
  int base = t * 8;
  int loc[8]; int s = 0;
  #pragma unroll
  for (int k = 0; k < 8; k++) {
    int cnt = 0;
    #pragma unroll
    for (int b = 0; b < 8; b++) cnt += partial[b * N_NODES + base + k];
    loc[k] = (cnt < K_SEL) ? 1 : 0;
    s += loc[k];
  }
  ps[t] = s; __syncthreads();
  for (int off = 1; off < 1024; off <<= 1) {
    int v = (t >= off) ? ps[t - off] : 0;
    __syncthreads();
    ps[t] += v;
    __syncthreads();
  }
  int pos = (t > 0) ? ps[t - 1] : 0;
  #pragma unroll
  for (int k = 0; k < 8; k++) {
    if (loc[k]) { idx[pos] = base + k; pos++; }
  }
}

// ============================================================================
// 6. C[m][n] = sum_k Af8[idx[m]][k] * At8[idx[n]][k] via MX-fp8 (scale=1.0).
//    256x256 tile, BK=128, NT2=64 K-tiles, 8 waves (2Mx4N),
//    mfma_scale_f32_32x32x64_f8f6f4 (e4m3), indexed staging (row = idx<<13).
//    TWO phases per K-tile. CORRECTED LEDGER (R8 race fix):
//      PhA: reads fa0,fb0 @top (covered: A0,B0(kt) retired @PhB(kt-1).VM4+SBAR);
//           stages {A0,B0}(kt+1); VM4 (retires {A1,B1}(kt)); SBAR;
//           READ fb1 HERE (now covered); lgkm(4) -> QUAD(0,0); lgkm(0) -> QUAD(0,1)
//      PhB: reads fa1 @top (covered: A1(kt) retired @PhA(kt).VM4+SBAR);
//           stages {A1,B1}(kt+1); VM4 (retires {A0,B0}(kt+1)); SBAR;
//           lgkm(0) -> QUAD(1,0) QUAD(1,1)
//    Peel (kt=63): fa0,fb0 @top; VM0; SBAR; fb1,fa1; lgkm(0); 4 QUADs.
// ============================================================================
#define NT2 64   // 8192 / 128

#define GLL(g, s) __builtin_amdgcn_global_load_lds( \
    (const __attribute__((address_space(1))) void*)(g), \
    (__attribute__((address_space(3))) void*)(s), 16, 0, 0)

#define STAGE_A(H, KTN, DSTP) \
  GLL(Af + aOf##H##0 + (size_t)(KTN) * 128, LDS + (DSTP) * 32768 + (H) * 16384 + t * 16); \
  GLL(Af + aOf##H##1 + (size_t)(KTN) * 128, LDS + (DSTP) * 32768 + (H) * 16384 + 8192 + t * 16);

#define STAGE_B(H, KTN, DSTP) \
  GLL(At + bOf##H##0 + (size_t)(KTN) * 128, LDS + 65536 + (DSTP) * 32768 + (H) * 16384 + t * 16); \
  GLL(At + bOf##H##1 + (size_t)(KTN) * 128, LDS + 65536 + (DSTP) * 32768 + (H) * 16384 + 8192 + t * 16);

#define VM4 asm volatile("s_waitcnt vmcnt(4)" ::: "memory");
#define VM0 asm volatile("s_waitcnt vmcnt(0)" ::: "memory");
#define SBAR asm volatile("s_barrier" ::: "memory");
#define LGKM0 asm volatile("s_waitcnt lgkmcnt(0)" ::: "memory"); __builtin_amdgcn_sched_barrier(0);
#define LGKM4 asm volatile("s_waitcnt lgkmcnt(4)" ::: "memory"); __builtin_amdgcn_sched_barrier(0);

// load one A-half: 2 m-frags x 2 k-steps x 32B (8 x ds_read_b128)
#define LDA8F(DST, PAB, MH) { \
  const u8* b_ = (PAB) + (MH) * 16384 + pA; \
  _Pragma("unroll") \
  for (int q = 0; q < 2; ++q) { \
    i32x4 x0 = *(const i32x4*)(b_ + q * 4096 + o00); \
    i32x4 x1 = *(const i32x4*)(b_ + q * 4096 + o01); \
    i32x4 y0 = *(const i32x4*)(b_ + q * 4096 + o10); \
    i32x4 y1 = *(const i32x4*)(b_ + q * 4096 + o11); \
    DST[q * 2 + 0] = __builtin_shufflevector(x0, x1, 0, 1, 2, 3, 4, 5, 6, 7); \
    DST[q * 2 + 1] = __builtin_shufflevector(y0, y1, 0, 1, 2, 3, 4, 5, 6, 7); } }

// load one B-half: 1 n-frag x 2 k-steps x 32B (4 x ds_read_b128)
#define LDB4F(DST, PBB, NH) { \
  const u8* b_ = (PBB) + (NH) * 16384 + pB; \
  i32x4 x0 = *(const i32x4*)(b_ + o00); \
  i32x4 x1 = *(const i32x4*)(b_ + o01); \
  i32x4 y0 = *(const i32x4*)(b_ + o10); \
  i32x4 y1 = *(const i32x4*)(b_ + o11); \
  DST[0] = __builtin_shufflevector(x0, x1, 0, 1, 2, 3, 4, 5, 6, 7); \
  DST[1] = __builtin_shufflevector(y0, y1, 0, 1, 2, 3, 4, 5, 6, 7); }

#define QUADF(MH, NH, FA, FB) \
  __builtin_amdgcn_s_setprio(1); \
  _Pragma("unroll") \
  for (int ks = 0; ks < 2; ++ks) \
    _Pragma("unroll") \
    for (int q = 0; q < 2; ++q) \
      acc[(MH) * 2 + q][NH] = __builtin_amdgcn_mfma_scale_f32_32x32x64_f8f6f4( \
          FA[q * 2 + ks], FB[ks], acc[(MH) * 2 + q][NH], 0, 0, \
          0, 0x7F7F7F7F, 0, 0x7F7F7F7F); \
  __builtin_amdgcn_s_setprio(0);

__global__ __launch_bounds__(512, 2) void gemm256(const u8* __restrict__ Af,
                                                  const u8* __restrict__ At,
                                                  const int* __restrict__ idxArr,
                                                  float* __restrict__ C) {
  __shared__ u8 LDS[131072];
  const int t = threadIdx.x, w = t >> 6, l = t & 63;
  const int l31 = l & 31, g = l >> 5;
  const int wm = w >> 2, wn = w & 3;   // 2M x 4N wave grid, per-wave out 128x64

  // T1: bijective XCD swizzle (256 blocks, 8 XCDs, 32 blocks/XCD)
  int orig = blockIdx.x;
  int wg = (orig & 7) * 32 + (orig >> 3);
  int bm = wg >> 4, bn = wg & 15;
  const int mi0 = bm * 256, ni0 = bn * 256;
  const size_t m0 = (size_t)mi0, n0 = (size_t)ni0;

  // indexed staging sources (inverse-swizzled chunk within the row)
  const int trow = t >> 3;                              // 0..63
  const int csw = ((t & 7) ^ (trow & 7)) * 16;          // swizzled 16B chunk
  const unsigned aOf00 = ((unsigned)idxArr[mi0 + trow] << 13) | csw;         // H0,s0
  const unsigned aOf01 = ((unsigned)idxArr[mi0 + trow + 128] << 13) | csw;   // H0,s1
  const unsigned aOf10 = ((unsigned)idxArr[mi0 + trow + 64] << 13) | csw;    // H1,s0
  const unsigned aOf11 = ((unsigned)idxArr[mi0 + trow + 192] << 13) | csw;   // H1,s1
  const int bRow = (t >> 8) * 64 + (trow & 31);
  const unsigned bOf00 = ((unsigned)idxArr[ni0 + bRow] << 13) | csw;         // H0,s0
  const unsigned bOf01 = ((unsigned)idxArr[ni0 + bRow + 128] << 13) | csw;   // H0,s1
  const unsigned bOf10 = ((unsigned)idxArr[ni0 + bRow + 32] << 13) | csw;    // H1,s0
  const unsigned bOf11 = ((unsigned)idxArr[ni0 + bRow + 160] << 13) | csw;   // H1,s1

  // fragment ds_read bases (bytes): row p*128 + swizzled slot
  const int pA = (wm * 64 + l31) * 128;
  const int pB = (wn * 32 + l31) * 128;
  const int k7 = l31 & 7;
  const int o00 = ((g * 2 + 0) ^ k7) * 16;   // ks=0, chunk 0
  const int o01 = ((g * 2 + 1) ^ k7) * 16;   // ks=0, chunk 1
  const int o10 = ((g * 2 + 4) ^ k7) * 16;   // ks=1, chunk 0
  const int o11 = ((g * 2 + 5) ^ k7) * 16;   // ks=1, chunk 1

  f32x16 acc[4][2];
  #pragma unroll
  for (int i = 0; i < 4; ++i)
    #pragma unroll
    for (int j = 0; j < 2; ++j)
      #pragma unroll
      for (int r = 0; r < 16; ++r) acc[i][j][r] = 0.f;

  i32x8 fa0[4], fa1[4], fb0[2], fb1[2];

  // prologue: stage tile 0 (A0,B0,A1,B1), drain, barrier
  STAGE_A(0, 0, 0) STAGE_B(0, 0, 0) STAGE_A(1, 0, 0) STAGE_B(1, 0, 0)
  VM0
  SBAR

  for (int kt = 0; kt < NT2 - 1; ++kt) {
    int p = kt & 1, pn = p ^ 1;
    const u8* PA = LDS + p * 32768;
    const u8* PB = LDS + 65536 + p * 32768;
    // PhA: fa0,fb0 @top (retired @PhB(kt-1)); stage A0,B0(kt+1); VM4 retires
    // {A1,B1}(kt); SBAR; THEN read fb1 (now safe); lgkm-split QUADs.
    LDA8F(fa0, PA, 0) LDB4F(fb0, PB, 0)
    STAGE_A(0, kt + 1, pn) STAGE_B(0, kt + 1, pn)
    VM4 SBAR
    LDB4F(fb1, PB, 1)
    LGKM4 QUADF(0, 0, fa0, fb0)
    LGKM0 QUADF(0, 1, fa0, fb1)
    // PhB: fa1 @top (A1(kt) retired @PhA.VM4+SBAR); stage A1,B1(kt+1); VM4
    // retires {A0,B0}(kt+1) for next PhA.
    LDA8F(fa1, PA, 1)
    STAGE_A(1, kt + 1, pn) STAGE_B(1, kt + 1, pn)
    VM4 SBAR
    LGKM0 QUADF(1, 0, fa1, fb0) QUADF(1, 1, fa1, fb1)
  }
  { // last tile (kt = 63, buf 1): full drain, then all reads
    const u8* PA = LDS + 32768;
    const u8* PB = LDS + 65536 + 32768;
    LDA8F(fa0, PA, 0) LDB4F(fb0, PB, 0)
    VM0 SBAR
    LDB4F(fb1, PB, 1) LDA8F(fa1, PA, 1)
    LGKM0
    QUADF(0, 0, fa0, fb0) QUADF(0, 1, fa0, fb1)
    QUADF(1, 0, fa1, fb0) QUADF(1, 1, fa1, fb1)
  }

  // epilogue: 32x32 C/D layout col=lane&31, row=(reg&3)+8*(reg>>2)+4*(lane>>5)
  #pragma unroll
  for (int mf = 0; mf < 4; ++mf) {
    #pragma unroll
    for (int nf = 0; nf < 2; ++nf) {
      #pragma unroll
      for (int r = 0; r < 16; ++r) {
        int row = (r & 3) + 8 * (r >> 2) + 4 * g;
        C[(m0 + wm * 128 + mf * 32 + row) * K_SEL + n0 + wn * 64 + nf * 32 + l31] =
            acc[mf][nf][r];
      }
    }
  }
}

// 7. X_pooled[m,f] = X[idx[m],f] * tanh(y[idx[m]])
__global__ void xpool(const float* __restrict__ X, const float* __restrict__ y,
                      const int* __restrict__ idx, float* __restrict__ out) {
  int m = blockIdx.x;
  int i = idx[m];
  float th = tanhf(y[i]);
  out[(size_t)m * F_DIM + threadIdx.x] = X[(size_t)i * F_DIM + threadIdx.x] * th;
}

extern "C" void kernel_launch(void* const* d_in, const int* in_sizes, int n_in,
                              void* d_out, int out_size, void* d_ws, size_t ws_size,
                              hipStream_t stream) {
  const float* X    = (const float*)d_in[0];
  const float* A    = (const float*)d_in[1];
  const float* kern = (const float*)d_in[2];
  float* out = (float*)d_out;
  float* Xp = out;                                 // 4096*256
  float* Ap = out + (size_t)K_SEL * F_DIM;         // 4096*4096

  char* ws = (char*)d_ws;
  float*  Xk      = (float*) (ws);                 // 8192 f32
  float*  yv      = (float*) (ws + 32 * 1024);     // 8192 f32
  int*    idx     = (int*)   (ws + 64 * 1024);     // 4096 i32
  int*    partial = (int*)   (ws + 128 * 1024);    // 8*8192 i32 = 256 KB
  double* ypart   = (double*)(ws + 512 * 1024);    // 32*8192 f64 = 2 MB
  u8* Af8 = (u8*)(ws + 4 * 1024 * 1024);                               // 64 MB
  u8* At8 = (u8*)(ws + 4 * 1024 * 1024 + (size_t)N_NODES * N_NODES);   // 64 MB

  xk_kernel  <<<N_NODES, 256, 0, stream>>>(X, kern, Xk);
  prep8      <<<dim3(N_NODES / PC, N_NODES / PR), 256, 0, stream>>>(A, Xk, Af8, At8, ypart);
  yreduce    <<<N_NODES / 256, 256, 0, stream>>>(ypart, yv);
  rank2d     <<<dim3(32, 8), 256, 0, stream>>>(yv, partial);
  scan_kernel<<<1, 1024, 0, stream>>>(partial, idx);
  gemm256    <<<256, 512, 0, stream>>>(Af8, At8, idx, Ap);
  xpool      <<<K_SEL, 256, 0, stream>>>(X, yv, idx, Xp);
}

// Round 11
// 194.582 us; speedup vs baseline: 1.2260x; 1.2260x over previous
//
#include <hip/hip_runtime.h>
#include <hip/hip_bf16.h>
#include <stdint.h>

#define N_NODES 8192
#define F_DIM 256
#define K_SEL 4096

typedef unsigned char u8;
typedef __attribute__((ext_vector_type(4))) int i32x4;
typedef __attribute__((ext_vector_type(8))) int i32x8;
typedef __attribute__((ext_vector_type(16))) float f32x16;

// fp4 e2m1 code for v in [0,1) pre-scaled by 4 (uniform MX scale 2^-2).
// grid (scaled): {0,.5,1,1.5,2,3,4} = codes 0..6; RNE.
static __device__ __forceinline__ int fp4code(float v) {
  float x4 = v * 4.0f;
  float c1 = __builtin_rintf(x4 * 2.0f);        // region [0,2): step .5
  float c2 = 4.0f + __builtin_rintf(x4 - 2.0f); // region [2,4]: step 1
  return (int)(x4 < 2.0f ? c1 : c2);
}

// 1. Xk[i] = sum_f X[i,f]*kernel[f]   (fp64 accumulate)
__global__ void xk_kernel(const float* __restrict__ X, const float* __restrict__ kern,
                          float* __restrict__ Xk) {
  __shared__ double red[256];
  int row = blockIdx.x, t = threadIdx.x;
  double p = (double)X[(size_t)row * F_DIM + t] * (double)kern[t];
  red[t] = p; __syncthreads();
  for (int off = 128; off > 0; off >>= 1) {
    if (t < off) red[t] += red[t + off];
    __syncthreads();
  }
  if (t == 0) Xk[row] = (float)red[0];
}

// 2. fused prep: ONE pass over A emits Af4 (row-major fp4 codes, packed
//    2/byte), At4 (transposed fp4), and per-chunk fp64 gemv partials.
#define PR 128
#define PC 256
__global__ __launch_bounds__(256) void prep4(const float* __restrict__ A,
                                             const float* __restrict__ Xk,
                                             u8* __restrict__ Af4,
                                             u8* __restrict__ At4,
                                             double* __restrict__ ypart) {
  __shared__ u8 tile[PR][PC + 4];   // fp4 codes, 1 B each
  __shared__ float sXk[PC];
  int t = threadIdx.x, w = t >> 6, l = t & 63;
  int c0 = blockIdx.x * PC, r0 = blockIdx.y * PR;
  if (t < PC / 4) *(float4*)&sXk[t * 4] = *(const float4*)&Xk[c0 + t * 4];
  __syncthreads();
  #pragma unroll
  for (int p = 0; p < 8; ++p) {
    int r = p * 16 + (t >> 4);
    const float4* src = (const float4*)(A + (size_t)(r0 + r) * N_NODES + c0);
    float4 v[4];
    #pragma unroll
    for (int j = 0; j < 4; ++j) v[j] = src[(t & 15) + j * 16];
    double d = 0.0;
    #pragma unroll
    for (int j = 0; j < 4; ++j) {
      int c4 = (t & 15) + j * 16;
      float4 x = *(const float4*)&sXk[c4 * 4];
      d += (double)v[j].x * x.x + (double)v[j].y * x.y +
           (double)v[j].z * x.z + (double)v[j].w * x.w;
      int pk = fp4code(v[j].x) | (fp4code(v[j].y) << 8) |
               (fp4code(v[j].z) << 16) | (fp4code(v[j].w) << 24);
      *(int*)&tile[r][c4 * 4] = pk;
    }
    d += __shfl_xor(d, 1); d += __shfl_xor(d, 2);
    d += __shfl_xor(d, 4); d += __shfl_xor(d, 8);
    if ((t & 15) == 0) ypart[(size_t)blockIdx.x * N_NODES + r0 + r] = d;
  }
  __syncthreads();
  // Af4 rows (R10 BUG FIX): 256 codes/row = 128 B. Lane l packs elements
  // l*4..l*4+3 -> ushort at byte (c0>>1)+l*2; 64 lanes x 2B = 128B exact.
  for (int j = w; j < PR; j += 4) {
    const u8* tr = tile[j];
    unsigned lo = (unsigned)(tr[l * 4 + 0] | (tr[l * 4 + 1] << 4));
    unsigned hi = (unsigned)(tr[l * 4 + 2] | (tr[l * 4 + 3] << 4));
    *(unsigned short*)(Af4 + (size_t)(r0 + j) * (N_NODES / 2) + (c0 >> 1) + l * 2) =
        (unsigned short)(lo | (hi << 8));
  }
  // At4 cols: lane l packs rows {2l,2l+1} -> 1 byte; 64B contiguous per col
  for (int j = w; j < PC; j += 4) {
    u8 b = (u8)(tile[2 * l][j] | (tile[2 * l + 1][j] << 4));
    At4[(size_t)(c0 + j) * (N_NODES / 2) + (r0 >> 1) + l] = b;
  }
}

// 3. y[i] = sum over 32 col-chunk partials (fp64, fixed order -> deterministic)
__global__ void yreduce(const double* __restrict__ ypart, float* __restrict__ y) {
  int i = blockIdx.x * 256 + threadIdx.x;
  double s = 0.0;
  #pragma unroll
  for (int b = 0; b < 32; ++b) s += ypart[(size_t)b * N_NODES + i];
  y[i] = (float)s;
}

// 4. partial ranks over j-chunks of 1024; 256 blocks -> full-chip
__global__ void rank2d(const float* __restrict__ y, int* __restrict__ partial) {
  __shared__ float sc[1024];
  int i = blockIdx.x * 256 + threadIdx.x;
  float si = y[i];
  int j0 = blockIdx.y * 1024;
  for (int c = threadIdx.x; c < 1024; c += 256) sc[c] = y[j0 + c];
  __syncthreads();
  int cnt = 0;
  #pragma unroll 8
  for (int jj = 0; jj < 1024; ++jj) {
    float sj = sc[jj];
    int j = j0 + jj;
    cnt += (sj > si) || (sj == si && j < i);
  }
  partial[blockIdx.y * N_NODES + i] = cnt;
}

// 5. sum partials; ordered compaction -> idx[0..K-1] ascending
__global__ void scan_kernel(const int* __restrict__ partial, int* __restrict__ idx) {
  __shared__ int ps[1024];
  int t = threadIdx.x;
  int base = t * 8;
  int loc[8]; int s = 0;
  #pragma unroll
  for (int k = 0; k < 8; k++) {
    int cnt = 0;
    #pragma unroll
    for (int b = 0; b < 8; b++) cnt += partial[b * N_NODES + base + k];
    loc[k] = (cnt < K_SEL) ? 1 : 0;
    s += loc[k];
  }
  ps[t] = s; __syncthreads();
  for (int off = 1; off < 1024; off <<= 1) {
    int v = (t >= off) ? ps[t - off] : 0;
    __syncthreads();
    ps[t] += v;
    __syncthreads();
  }
  int pos = (t > 0) ? ps[t - 1] : 0;
  #pragma unroll
  for (int k = 0; k < 8; k++) {
    if (loc[k]) { idx[pos] = base + k; pos++; }
  }
}

// ============================================================================
// 6. C[m][n] = sum_k A[idx[m]][k]*A[k][idx[n]] via MX-fp4 (uniform scale 2^-2).
//    256x256 tile, BK=256 K (128 B/row — BYTE-IDENTICAL geometry to the
//    verified fp8 BK=128 kernel), NT2=32 tiles, 8 waves (2Mx4N),
//    mfma_scale_f32_32x32x64_f8f6f4 cbsz=blgp=4 (fp4), scale 0x7D (2^-2).
//    Same verified 2-phase schedule + VM4 ledger + LGKM4 split as R9.
//    Row shift 12 (4096 B/row). 8 MFMAs/QUAD (4 k-steps x 2 m-frags).
// ============================================================================
#define NT2 32   // 8192 / 256

#define GLL(g, s) __builtin_amdgcn_global_load_lds( \
    (const __attribute__((address_space(1))) void*)(g), \
    (__attribute__((address_space(3))) void*)(s), 16, 0, 0)

#define STAGE_A(H, KTN, DSTP) \
  GLL(Af + aOf##H##0 + (size_t)(KTN) * 128, LDS + (DSTP) * 32768 + (H) * 16384 + t * 16); \
  GLL(Af + aOf##H##1 + (size_t)(KTN) * 128, LDS + (DSTP) * 32768 + (H) * 16384 + 8192 + t * 16);

#define STAGE_B(H, KTN, DSTP) \
  GLL(At + bOf##H##0 + (size_t)(KTN) * 128, LDS + 65536 + (DSTP) * 32768 + (H) * 16384 + t * 16); \
  GLL(At + bOf##H##1 + (size_t)(KTN) * 128, LDS + 65536 + (DSTP) * 32768 + (H) * 16384 + 8192 + t * 16);

#define VM4 asm volatile("s_waitcnt vmcnt(4)" ::: "memory");
#define VM0 asm volatile("s_waitcnt vmcnt(0)" ::: "memory");
#define SBAR asm volatile("s_barrier" ::: "memory");
#define LGKM0 asm volatile("s_waitcnt lgkmcnt(0)" ::: "memory"); __builtin_amdgcn_sched_barrier(0);
#define LGKM4 asm volatile("s_waitcnt lgkmcnt(4)" ::: "memory"); __builtin_amdgcn_sched_barrier(0);

// load one A-half: 2 m-frags x 4 k-steps x 16B (8 x ds_read_b128)
#define LDA8F(DST, PAB, MH) { \
  const u8* b_ = (PAB) + (MH) * 16384 + pA; \
  _Pragma("unroll") \
  for (int q = 0; q < 2; ++q) \
    _Pragma("unroll") \
    for (int ks = 0; ks < 4; ++ks) \
      DST[q * 4 + ks] = *(const i32x4*)(b_ + q * 4096 + oks[ks]); }

// load one B-half: 1 n-frag x 4 k-steps x 16B (4 x ds_read_b128)
#define LDB4F(DST, PBB, NH) { \
  const u8* b_ = (PBB) + (NH) * 16384 + pB; \
  _Pragma("unroll") \
  for (int ks = 0; ks < 4; ++ks) \
    DST[ks] = *(const i32x4*)(b_ + oks[ks]); }

#define EXT8(x) __builtin_shufflevector(x, x, 0, 1, 2, 3, -1, -1, -1, -1)

#define QUADF(MH, NH, FA, FB) \
  __builtin_amdgcn_s_setprio(1); \
  _Pragma("unroll") \
  for (int ks = 0; ks < 4; ++ks) \
    _Pragma("unroll") \
    for (int q = 0; q < 2; ++q) \
      acc[(MH) * 2 + q][NH] = __builtin_amdgcn_mfma_scale_f32_32x32x64_f8f6f4( \
          EXT8(FA[q * 4 + ks]), EXT8(FB[ks]), acc[(MH) * 2 + q][NH], 4, 4, \
          0, 0x7D7D7D7D, 0, 0x7D7D7D7D); \
  __builtin_amdgcn_s_setprio(0);

__global__ __launch_bounds__(512, 2) void gemm256(const u8* __restrict__ Af,
                                                  const u8* __restrict__ At,
                                                  const int* __restrict__ idxArr,
                                                  float* __restrict__ C) {
  __shared__ u8 LDS[131072];
  const int t = threadIdx.x, w = t >> 6, l = t & 63;
  const int l31 = l & 31, g = l >> 5;
  const int wm = w >> 2, wn = w & 3;   // 2M x 4N wave grid, per-wave out 128x64

  // T1: bijective XCD swizzle (256 blocks, 8 XCDs, 32 blocks/XCD)
  int orig = blockIdx.x;
  int wg = (orig & 7) * 32 + (orig >> 3);
  int bm = wg >> 4, bn = wg & 15;
  const int mi0 = bm * 256, ni0 = bn * 256;
  const size_t m0 = (size_t)mi0, n0 = (size_t)ni0;

  // indexed staging sources (row = idx<<12 bytes; inverse-swizzled chunk)
  const int trow = t >> 3;                              // 0..63
  const int csw = ((t & 7) ^ (trow & 7)) * 16;          // swizzled 16B chunk
  const unsigned aOf00 = ((unsigned)idxArr[mi0 + trow] << 12) | csw;         // H0,s0
  const unsigned aOf01 = ((unsigned)idxArr[mi0 + trow + 128] << 12) | csw;   // H0,s1
  const unsigned aOf10 = ((unsigned)idxArr[mi0 + trow + 64] << 12) | csw;    // H1,s0
  const unsigned aOf11 = ((unsigned)idxArr[mi0 + trow + 192] << 12) | csw;   // H1,s1
  const int bRow = (t >> 8) * 64 + (trow & 31);
  const unsigned bOf00 = ((unsigned)idxArr[ni0 + bRow] << 12) | csw;         // H0,s0
  const unsigned bOf01 = ((unsigned)idxArr[ni0 + bRow + 128] << 12) | csw;   // H0,s1
  const unsigned bOf10 = ((unsigned)idxArr[ni0 + bRow + 32] << 12) | csw;    // H1,s0
  const unsigned bOf11 = ((unsigned)idxArr[ni0 + bRow + 160] << 12) | csw;   // H1,s1

  // fragment ds_read bases (bytes): row 128 B, swizzled 16B chunk per k-step
  const int pA = (wm * 64 + l31) * 128;
  const int pB = (wn * 32 + l31) * 128;
  const int k7 = l31 & 7;
  int oks[4];
  #pragma unroll
  for (int ks = 0; ks < 4; ++ks) oks[ks] = ((ks * 2 + g) ^ k7) * 16;

  f32x16 acc[4][2];
  #pragma unroll
  for (int i = 0; i < 4; ++i)
    #pragma unroll
    for (int j = 0; j < 2; ++j)
      #pragma unroll
      for (int r = 0; r < 16; ++r) acc[i][j][r] = 0.f;

  i32x4 fa0[8], fa1[8], fb0[4], fb1[4];

  // prologue: stage tile 0 (A0,B0,A1,B1), drain, barrier
  STAGE_A(0, 0, 0) STAGE_B(0, 0, 0) STAGE_A(1, 0, 0) STAGE_B(1, 0, 0)
  VM0
  SBAR

  for (int kt = 0; kt < NT2 - 1; ++kt) {
    int p = kt & 1, pn = p ^ 1;
    const u8* PA = LDS + p * 32768;
    const u8* PB = LDS + 65536 + p * 32768;
    // PhA: fa0,fb0 @top (retired @PhB(kt-1)); stage A0,B0(kt+1); VM4 retires
    // {A1,B1}(kt); SBAR; THEN read fb1; lgkm-split QUADs.
    LDA8F(fa0, PA, 0) LDB4F(fb0, PB, 0)
    STAGE_A(0, kt + 1, pn) STAGE_B(0, kt + 1, pn)
    VM4 SBAR
    LDB4F(fb1, PB, 1)
    LGKM4 QUADF(0, 0, fa0, fb0)
    LGKM0 QUADF(0, 1, fa0, fb1)
    // PhB: fa1 @top (A1(kt) retired @PhA.VM4+SBAR); stage A1,B1(kt+1); VM4
    // retires {A0,B0}(kt+1) for next PhA.
    LDA8F(fa1, PA, 1)
    STAGE_A(1, kt + 1, pn) STAGE_B(1, kt + 1, pn)
    VM4 SBAR
    LGKM0 QUADF(1, 0, fa1, fb0) QUADF(1, 1, fa1, fb1)
  }
  { // last tile (kt = 31, buf 1): full drain, then all reads
    const u8* PA = LDS + 32768;
    const u8* PB = LDS + 65536 + 32768;
    LDA8F(fa0, PA, 0) LDB4F(fb0, PB, 0)
    VM0 SBAR
    LDB4F(fb1, PB, 1) LDA8F(fa1, PA, 1)
    LGKM0
    QUADF(0, 0, fa0, fb0) QUADF(0, 1, fa0, fb1)
    QUADF(1, 0, fa1, fb0) QUADF(1, 1, fa1, fb1)
  }

  // epilogue: 32x32 C/D layout col=lane&31, row=(reg&3)+8*(reg>>2)+4*(lane>>5)
  #pragma unroll
  for (int mf = 0; mf < 4; ++mf) {
    #pragma unroll
    for (int nf = 0; nf < 2; ++nf) {
      #pragma unroll
      for (int r = 0; r < 16; ++r) {
        int row = (r & 3) + 8 * (r >> 2) + 4 * g;
        C[(m0 + wm * 128 + mf * 32 + row) * K_SEL + n0 + wn * 64 + nf * 32 + l31] =
            acc[mf][nf][r];
      }
    }
  }
}

// 7. X_pooled[m,f] = X[idx[m],f] * tanh(y[idx[m]])
__global__ void xpool(const float* __restrict__ X, const float* __restrict__ y,
                      const int* __restrict__ idx, float* __restrict__ out) {
  int m = blockIdx.x;
  int i = idx[m];
  float th = tanhf(y[i]);
  out[(size_t)m * F_DIM + threadIdx.x] = X[(size_t)i * F_DIM + threadIdx.x] * th;
}

extern "C" void kernel_launch(void* const* d_in, const int* in_sizes, int n_in,
                              void* d_out, int out_size, void* d_ws, size_t ws_size,
                              hipStream_t stream) {
  const float* X    = (const float*)d_in[0];
  const float* A    = (const float*)d_in[1];
  const float* kern = (const float*)d_in[2];
  float* out = (float*)d_out;
  float* Xp = out;                                 // 4096*256
  float* Ap = out + (size_t)K_SEL * F_DIM;         // 4096*4096

  char* ws = (char*)d_ws;
  float*  Xk      = (float*) (ws);                 // 8192 f32
  float*  yv      = (float*) (ws + 32 * 1024);     // 8192 f32
  int*    idx     = (int*)   (ws + 64 * 1024);     // 4096 i32
  int*    partial = (int*)   (ws + 128 * 1024);    // 8*8192 i32 = 256 KB
  double* ypart   = (double*)(ws + 512 * 1024);    // 32*8192 f64 = 2 MB
  u8* Af4 = (u8*)(ws + 4 * 1024 * 1024);                                   // 32 MB
  u8* At4 = (u8*)(ws + 4 * 1024 * 1024 + (size_t)N_NODES * N_NODES / 2);   // 32 MB

  xk_kernel  <<<N_NODES, 256, 0, stream>>>(X, kern, Xk);
  prep4      <<<dim3(N_NODES / PC, N_NODES / PR), 256, 0, stream>>>(A, Xk, Af4, At4, ypart);
  yreduce    <<<N_NODES / 256, 256, 0, stream>>>(ypart, yv);
  rank2d     <<<dim3(32, 8), 256, 0, stream>>>(yv, partial);
  scan_kernel<<<1, 1024, 0, stream>>>(partial, idx);
  gemm256    <<<256, 512, 0, stream>>>(Af4, At4, idx, Ap);
  xpool      <<<K_SEL, 256, 0, stream>>>(X, yv, idx, Xp);
}